// Round 3
// baseline (444.787 us; speedup 1.0000x reference)
//
#include <hip/hip_runtime.h>

#define DIM 32
#define SCAN_THREADS 1024

// ---------------- sorted (pull) path ----------------

__global__ void zero_i32_kernel(int* __restrict__ p, int n) {
    int t = blockIdx.x * blockDim.x + threadIdx.x;
    if (t < n) p[t] = 0;
}

__global__ void hist_kernel(const int* __restrict__ dst, int* __restrict__ counts,
                            int n_edges) {
    int t = blockIdx.x * blockDim.x + threadIdx.x;
    if (t < n_edges) atomicAdd(&counts[dst[t]], 1);
}

// Single-block exclusive scan: counts[n] -> offsets[n].
// Each thread serially scans a contiguous chunk; chunk totals scanned in LDS.
__global__ void scan_kernel(const int* __restrict__ counts, int* __restrict__ offsets,
                            int n) {
    __shared__ int sh[SCAN_THREADS];
    int tid = threadIdx.x;
    int chunk = (n + SCAN_THREADS - 1) / SCAN_THREADS;
    int begin = tid * chunk;
    int end   = min(begin + chunk, n);
    int s = 0;
    for (int i = begin; i < end; ++i) s += counts[i];
    sh[tid] = s;
    __syncthreads();
    // Hillis-Steele inclusive scan over chunk totals
    for (int off = 1; off < SCAN_THREADS; off <<= 1) {
        int v = (tid >= off) ? sh[tid - off] : 0;
        __syncthreads();
        sh[tid] += v;
        __syncthreads();
    }
    int running = (tid == 0) ? 0 : sh[tid - 1];  // exclusive prefix of this chunk
    for (int i = begin; i < end; ++i) {
        offsets[i] = running;
        running += counts[i];
    }
}

// Scatter src values into dst-sorted order. cursors starts as exclusive
// offsets and is destroyed: afterwards cursors[n] == segment END of node n.
__global__ void scatter_sort_kernel(const int* __restrict__ src,
                                    const int* __restrict__ dst,
                                    int* __restrict__ cursors,
                                    int* __restrict__ sorted_src,
                                    int n_edges) {
    int t = blockIdx.x * blockDim.x + threadIdx.x;
    if (t < n_edges) {
        int pos = atomicAdd(&cursors[dst[t]], 1);
        sorted_src[pos] = src[t];
    }
}

// 32 lanes per node: lane f sums x[s*32+f] over the node's in-edge segment.
// Row gather = one coalesced 128B transaction per edge per node-group.
__global__ void aggregate_kernel(const float* __restrict__ x,
                                 const int* __restrict__ seg_end,
                                 const int* __restrict__ sorted_src,
                                 float* __restrict__ out,
                                 int n_out) {
    int t = blockIdx.x * blockDim.x + threadIdx.x;
    if (t >= n_out) return;
    int n = t >> 5;
    int f = t & 31;
    int end   = seg_end[n];
    int start = (n == 0) ? 0 : seg_end[n - 1];
    float acc = 0.0f;
    int k = start;
    // 4-way unroll: 4 independent index loads then 4 gathers in flight
    for (; k + 3 < end; k += 4) {
        int s0 = sorted_src[k];
        int s1 = sorted_src[k + 1];
        int s2 = sorted_src[k + 2];
        int s3 = sorted_src[k + 3];
        acc += x[s0 * DIM + f];
        acc += x[s1 * DIM + f];
        acc += x[s2 * DIM + f];
        acc += x[s3 * DIM + f];
    }
    for (; k < end; ++k) acc += x[sorted_src[k] * DIM + f];
    int deg = end - start;
    out[t] = acc / (float)max(deg, 1);
}

// ---------------- fallback (round-1 atomic) path ----------------

__global__ void zero_kernel(float* __restrict__ out, float* __restrict__ deg,
                            int n_out, int n_nodes) {
    int stride = gridDim.x * blockDim.x;
    for (int t = blockIdx.x * blockDim.x + threadIdx.x; t < n_out; t += stride)
        out[t] = 0.0f;
    for (int t = blockIdx.x * blockDim.x + threadIdx.x; t < n_nodes; t += stride)
        deg[t] = 0.0f;
}

__global__ void scatter_kernel(const float* __restrict__ x,
                               const int* __restrict__ src,
                               const int* __restrict__ dst,
                               float* __restrict__ out,
                               float* __restrict__ deg,
                               int n_edges) {
    long long t = (long long)blockIdx.x * blockDim.x + threadIdx.x;
    long long total = (long long)n_edges * DIM;
    if (t >= total) return;
    int e = (int)(t >> 5);
    int f = (int)(t & 31);
    float v = x[(long long)src[e] * DIM + f];
    atomicAdd(&out[(long long)dst[e] * DIM + f], v);
    if (f == 0) atomicAdd(&deg[dst[e]], 1.0f);
}

__global__ void div_kernel(float* __restrict__ out, const float* __restrict__ deg,
                           int n_out) {
    int t = blockIdx.x * blockDim.x + threadIdx.x;
    if (t >= n_out) return;
    out[t] = out[t] / fmaxf(deg[t >> 5], 1.0f);
}

// ---------------- launch ----------------

extern "C" void kernel_launch(void* const* d_in, const int* in_sizes, int n_in,
                              void* d_out, int out_size, void* d_ws, size_t ws_size,
                              hipStream_t stream) {
    const float* x   = (const float*)d_in[0];
    const int*   src = (const int*)d_in[1];
    const int*   dst = (const int*)d_in[2];
    float* out = (float*)d_out;

    int n_nodes = in_sizes[0] / DIM;
    int n_edges = in_sizes[1];
    int n_out   = out_size;

    size_t need = (size_t)(2 * n_nodes + n_edges) * sizeof(int);
    if (ws_size >= need) {
        int* counts     = (int*)d_ws;              // [n_nodes]
        int* offsets    = counts + n_nodes;        // [n_nodes] -> becomes seg ends
        int* sorted_src = offsets + n_nodes;       // [n_edges]

        int nb = (n_nodes + 255) / 256;
        zero_i32_kernel<<<nb, 256, 0, stream>>>(counts, n_nodes);

        int eb = (n_edges + 255) / 256;
        hist_kernel<<<eb, 256, 0, stream>>>(dst, counts, n_edges);
        scan_kernel<<<1, SCAN_THREADS, 0, stream>>>(counts, offsets, n_nodes);
        scatter_sort_kernel<<<eb, 256, 0, stream>>>(src, dst, offsets, sorted_src,
                                                    n_edges);
        int ab = (n_out + 255) / 256;
        aggregate_kernel<<<ab, 256, 0, stream>>>(x, offsets, sorted_src, out, n_out);
    } else {
        // fallback: atomic scatter (round-1 path), needs n_nodes floats in ws
        float* deg = (float*)d_ws;
        int threads = 256;
        int blocks  = (n_out + threads - 1) / threads;
        zero_kernel<<<blocks, threads, 0, stream>>>(out, deg, n_out, n_nodes);
        long long total = (long long)n_edges * DIM;
        int sblocks = (int)((total + threads - 1) / threads);
        scatter_kernel<<<sblocks, threads, 0, stream>>>(x, src, dst, out, deg,
                                                        n_edges);
        div_kernel<<<blocks, threads, 0, stream>>>(out, deg, n_out);
    }
}

// Round 4
// 302.498 us; speedup vs baseline: 1.4704x; 1.4704x over previous
//
#include <hip/hip_runtime.h>

#define DIM 32
#define TILE 8192          // scan tile: 256 threads x 32 elements

// ---------------- sorted (pull) path ----------------

__global__ void zero_i32_kernel(int* __restrict__ p, int n) {
    int t = blockIdx.x * blockDim.x + threadIdx.x;
    if (t < n) p[t] = 0;
}

__global__ void hist_kernel(const int* __restrict__ dst, int* __restrict__ counts,
                            int n_edges) {
    int t = blockIdx.x * blockDim.x + threadIdx.x;
    if (t < n_edges) atomicAdd(&counts[dst[t]], 1);
}

// ---- two-level scan: counts[n] -> exclusive offsets[n] ----

// pass 1: per-block tile sums
__global__ void scan_part1(const int* __restrict__ counts,
                           int* __restrict__ block_sums, int n) {
    __shared__ int sh[256];
    int base = blockIdx.x * TILE + threadIdx.x * 32;
    int s = 0;
#pragma unroll
    for (int i = 0; i < 32; ++i) {
        int idx = base + i;
        if (idx < n) s += counts[idx];
    }
    sh[threadIdx.x] = s;
    __syncthreads();
    for (int off = 128; off > 0; off >>= 1) {
        if (threadIdx.x < off) sh[threadIdx.x] += sh[threadIdx.x + off];
        __syncthreads();
    }
    if (threadIdx.x == 0) block_sums[blockIdx.x] = sh[0];
}

// pass 2: exclusive scan of the (small) block-sum array, single thread
__global__ void scan_part2(int* __restrict__ block_sums, int nb) {
    if (blockIdx.x == 0 && threadIdx.x == 0) {
        int run = 0;
        for (int i = 0; i < nb; ++i) {
            int v = block_sums[i];
            block_sums[i] = run;
            run += v;
        }
    }
}

// pass 3: per-tile exclusive scan + block offset
__global__ void scan_part3(const int* __restrict__ counts,
                           const int* __restrict__ block_sums,
                           int* __restrict__ offsets, int n) {
    __shared__ int sh[256];
    int tid = threadIdx.x;
    int base = blockIdx.x * TILE + tid * 32;
    int local[32];
    int s = 0;
#pragma unroll
    for (int i = 0; i < 32; ++i) {
        int idx = base + i;
        int v = (idx < n) ? counts[idx] : 0;
        local[i] = v;
        s += v;
    }
    sh[tid] = s;
    __syncthreads();
    // Hillis-Steele inclusive scan over per-thread sums
    for (int off = 1; off < 256; off <<= 1) {
        int v = (tid >= off) ? sh[tid - off] : 0;
        __syncthreads();
        sh[tid] += v;
        __syncthreads();
    }
    int run = block_sums[blockIdx.x] + ((tid == 0) ? 0 : sh[tid - 1]);
#pragma unroll
    for (int i = 0; i < 32; ++i) {
        int idx = base + i;
        if (idx < n) offsets[idx] = run;
        run += local[i];
    }
}

// Scatter src values into dst-sorted order. cursors starts as exclusive
// offsets and is destroyed: afterwards cursors[n] == segment END of node n.
__global__ void scatter_sort_kernel(const int* __restrict__ src,
                                    const int* __restrict__ dst,
                                    int* __restrict__ cursors,
                                    int* __restrict__ sorted_src,
                                    int n_edges) {
    int t = blockIdx.x * blockDim.x + threadIdx.x;
    if (t < n_edges) {
        int pos = atomicAdd(&cursors[dst[t]], 1);
        sorted_src[pos] = src[t];
    }
}

// 8 lanes per node; lane owns 4 features (float4). x-row gather = 8 lanes x
// 16B = one 128B transaction; index load broadcasts across the 8-lane group.
__global__ void aggregate_kernel(const float* __restrict__ x,
                                 const int* __restrict__ seg_end,
                                 const int* __restrict__ sorted_src,
                                 float4* __restrict__ out,
                                 int n_nodes) {
    int t = blockIdx.x * blockDim.x + threadIdx.x;   // one thread per (node, 4-feat)
    int n = t >> 3;
    if (n >= n_nodes) return;
    int q = t & 7;                                   // which float4 of the row
    int end   = seg_end[n];
    int start = (n == 0) ? 0 : seg_end[n - 1];
    const float4* x4 = (const float4*)x;
    float4 acc0 = make_float4(0.f, 0.f, 0.f, 0.f);
    float4 acc1 = make_float4(0.f, 0.f, 0.f, 0.f);
    int k = start;
    for (; k + 1 < end; k += 2) {
        int s0 = sorted_src[k];
        int s1 = sorted_src[k + 1];
        float4 v0 = x4[s0 * 8 + q];
        float4 v1 = x4[s1 * 8 + q];
        acc0.x += v0.x; acc0.y += v0.y; acc0.z += v0.z; acc0.w += v0.w;
        acc1.x += v1.x; acc1.y += v1.y; acc1.z += v1.z; acc1.w += v1.w;
    }
    if (k < end) {
        int s0 = sorted_src[k];
        float4 v0 = x4[s0 * 8 + q];
        acc0.x += v0.x; acc0.y += v0.y; acc0.z += v0.z; acc0.w += v0.w;
    }
    float inv = 1.0f / (float)max(end - start, 1);
    float4 r;
    r.x = (acc0.x + acc1.x) * inv;
    r.y = (acc0.y + acc1.y) * inv;
    r.z = (acc0.z + acc1.z) * inv;
    r.w = (acc0.w + acc1.w) * inv;
    out[n * 8 + q] = r;
}

// ---------------- fallback (round-1 atomic) path ----------------

__global__ void zero_kernel(float* __restrict__ out, float* __restrict__ deg,
                            int n_out, int n_nodes) {
    int stride = gridDim.x * blockDim.x;
    for (int t = blockIdx.x * blockDim.x + threadIdx.x; t < n_out; t += stride)
        out[t] = 0.0f;
    for (int t = blockIdx.x * blockDim.x + threadIdx.x; t < n_nodes; t += stride)
        deg[t] = 0.0f;
}

__global__ void scatter_kernel(const float* __restrict__ x,
                               const int* __restrict__ src,
                               const int* __restrict__ dst,
                               float* __restrict__ out,
                               float* __restrict__ deg,
                               int n_edges) {
    long long t = (long long)blockIdx.x * blockDim.x + threadIdx.x;
    long long total = (long long)n_edges * DIM;
    if (t >= total) return;
    int e = (int)(t >> 5);
    int f = (int)(t & 31);
    float v = x[(long long)src[e] * DIM + f];
    atomicAdd(&out[(long long)dst[e] * DIM + f], v);
    if (f == 0) atomicAdd(&deg[dst[e]], 1.0f);
}

__global__ void div_kernel(float* __restrict__ out, const float* __restrict__ deg,
                           int n_out) {
    int t = blockIdx.x * blockDim.x + threadIdx.x;
    if (t >= n_out) return;
    out[t] = out[t] / fmaxf(deg[t >> 5], 1.0f);
}

// ---------------- launch ----------------

extern "C" void kernel_launch(void* const* d_in, const int* in_sizes, int n_in,
                              void* d_out, int out_size, void* d_ws, size_t ws_size,
                              hipStream_t stream) {
    const float* x   = (const float*)d_in[0];
    const int*   src = (const int*)d_in[1];
    const int*   dst = (const int*)d_in[2];
    float* out = (float*)d_out;

    int n_nodes = in_sizes[0] / DIM;
    int n_edges = in_sizes[1];
    int n_out   = out_size;

    int nb = (n_nodes + TILE - 1) / TILE;
    size_t need = (size_t)(2 * n_nodes + n_edges + nb) * sizeof(int);
    if (ws_size >= need) {
        int* counts     = (int*)d_ws;              // [n_nodes]
        int* offsets    = counts + n_nodes;        // [n_nodes] -> becomes seg ends
        int* sorted_src = offsets + n_nodes;       // [n_edges]
        int* block_sums = sorted_src + n_edges;    // [nb]

        int nblk = (n_nodes + 255) / 256;
        zero_i32_kernel<<<nblk, 256, 0, stream>>>(counts, n_nodes);

        int eb = (n_edges + 255) / 256;
        hist_kernel<<<eb, 256, 0, stream>>>(dst, counts, n_edges);

        scan_part1<<<nb, 256, 0, stream>>>(counts, block_sums, n_nodes);
        scan_part2<<<1, 64, 0, stream>>>(block_sums, nb);
        scan_part3<<<nb, 256, 0, stream>>>(counts, block_sums, offsets, n_nodes);

        scatter_sort_kernel<<<eb, 256, 0, stream>>>(src, dst, offsets, sorted_src,
                                                    n_edges);
        int athreads = n_nodes * 8;                // 8 lanes per node
        int ab = (athreads + 255) / 256;
        aggregate_kernel<<<ab, 256, 0, stream>>>(x, offsets, sorted_src,
                                                 (float4*)out, n_nodes);
    } else {
        // fallback: atomic scatter (round-1 path), needs n_nodes floats in ws
        float* deg = (float*)d_ws;
        int threads = 256;
        int blocks  = (n_out + threads - 1) / threads;
        zero_kernel<<<blocks, threads, 0, stream>>>(out, deg, n_out, n_nodes);
        long long total = (long long)n_edges * DIM;
        int sblocks = (int)((total + threads - 1) / threads);
        scatter_kernel<<<sblocks, threads, 0, stream>>>(x, src, dst, out, deg,
                                                        n_edges);
        div_kernel<<<blocks, threads, 0, stream>>>(out, deg, n_out);
    }
}